// Round 1
// baseline (105.079 us; speedup 1.0000x reference)
//
#include <hip/hip_runtime.h>
#include <math.h>

// Poincare-ball KG scoring kernel (MuRP-style) for MI355X.
// One 32-lane group per output element: 32 lanes x float4 == one 512B row.

#define EPSF 1e-5f
#define MAXN (1.0f - 1e-5f)

__device__ __forceinline__ float dot4(const float4 a, const float4 b) {
    return a.x * b.x + a.y * b.y + a.z * b.z + a.w * b.w;
}

__global__ __launch_bounds__(256) void poincare_score_kernel(
    const float* __restrict__ Eh, const float* __restrict__ rvh,
    const float* __restrict__ W, const float* __restrict__ bias0,
    const float* __restrict__ bias1, const int* __restrict__ head_idx,
    const int* __restrict__ rel_idx, const int* __restrict__ tail_idx,
    float* __restrict__ out, int total)
{
    const int group = threadIdx.x >> 5;
    const int lane  = threadIdx.x & 31;
    const int e     = blockIdx.x * 8 + group;
    if (e >= total) return;

    const int hi = head_idx[e];
    const int ri = rel_idx[e];
    const int ti = tail_idx[e];

    const float4* Eh4  = reinterpret_cast<const float4*>(Eh);
    const float4* rvh4 = reinterpret_cast<const float4*>(rvh);
    const float4* W4   = reinterpret_cast<const float4*>(W);

    float4 h = Eh4[(size_t)hi * 32 + lane];
    float4 t = Eh4[(size_t)ti * 32 + lane];
    float4 r = rvh4[(size_t)ri * 32 + lane];
    float4 w = W4[(size_t)ri * 32 + lane];

    // ---- reduction round 1: h2, t2, r2 (batched for ILP) ----
    float h2 = dot4(h, h);
    float t2 = dot4(t, t);
    float r2 = dot4(r, r);
#pragma unroll
    for (int m = 16; m; m >>= 1) {
        h2 += __shfl_xor(h2, m);
        t2 += __shfl_xor(t2, m);
        r2 += __shfl_xor(r2, m);
    }

    // ---- norm_within_one on h, t, r (track squared norms analytically) ----
    float nh = sqrtf(h2 + 1e-15f);
    float sh = (nh > MAXN) ? (MAXN / nh) : 1.0f;
    h.x *= sh; h.y *= sh; h.z *= sh; h.w *= sh; h2 *= sh * sh;

    float nt = sqrtf(t2 + 1e-15f);
    float st = (nt > MAXN) ? (MAXN / nt) : 1.0f;
    t.x *= st; t.y *= st; t.z *= st; t.w *= st; t2 *= st * st;

    float nr = sqrtf(r2 + 1e-15f);
    float sr = (nr > MAXN) ? (MAXN / nr) : 1.0f;
    r.x *= sr; r.y *= sr; r.z *= sr; r.w *= sr; r2 *= sr * sr;

    // ---- p_log_map(h): artanh(n)/n * h ; then elementwise * w ----
    float nl = sqrtf(h2 + 1e-15f);
    nl = fminf(fmaxf(nl, EPSF), MAXN);
    float lf = 0.5f * logf((1.0f + nl) / (1.0f - nl)) / nl;  // artanh(n)/n

    float4 v;
    v.x = lf * h.x * w.x;
    v.y = lf * h.y * w.y;
    v.z = lf * h.z * w.z;
    v.w = lf * h.w * w.w;

    // ---- reduction round 2: ||v||^2 and t.r (batched) ----
    float v2 = dot4(v, v);
    float xy = dot4(t, r);
#pragma unroll
    for (int m = 16; m; m >>= 1) {
        v2 += __shfl_xor(v2, m);
        xy += __shfl_xor(xy, m);
    }

    // ---- p_exp_map(v): tanh(n)/n * v ----
    float nv = fmaxf(sqrtf(v2 + 1e-15f), EPSF);
    float ef = tanhf(nv) / nv;
    float4 hd;
    hd.x = ef * v.x; hd.y = ef * v.y; hd.z = ef * v.z; hd.w = ef * v.w;
    float hd2 = ef * ef * v2;

    // norm_within_one(head)
    float nhd = sqrtf(hd2 + 1e-15f);
    float shd = (nhd > MAXN) ? (MAXN / nhd) : 1.0f;
    hd.x *= shd; hd.y *= shd; hd.z *= shd; hd.w *= shd; hd2 *= shd * shd;

    // ---- p_sum(t, r): Mobius addition ----
    float ct  = 1.0f + 2.0f * xy + r2;          // coeff of t
    float cr  = 1.0f - t2;                      // coeff of r
    float den = 1.0f + 2.0f * xy + t2 * r2;
    den = fmaxf(den, EPSF);
    float id = 1.0f / den;
    float4 tl;
    tl.x = (ct * t.x + cr * r.x) * id;
    tl.y = (ct * t.y + cr * r.y) * id;
    tl.z = (ct * t.z + cr * r.z) * id;
    tl.w = (ct * t.w + cr * r.w) * id;

    // ---- reduction round 3: ||tail||^2 ----
    float tl2 = dot4(tl, tl);
#pragma unroll
    for (int m = 16; m; m >>= 1) tl2 += __shfl_xor(tl2, m);

    // norm_within_one(tail)
    float ntl = sqrtf(tl2 + 1e-15f);
    float stl = (ntl > MAXN) ? (MAXN / ntl) : 1.0f;
    tl.x *= stl; tl.y *= stl; tl.z *= stl; tl.w *= stl; tl2 *= stl * stl;

    // ---- reduction round 4: ||head - tail||^2 ----
    float dx = hd.x - tl.x, dy = hd.y - tl.y, dz = hd.z - tl.z, dw = hd.w - tl.w;
    float d2 = dx * dx + dy * dy + dz * dz + dw * dw;
#pragma unroll
    for (int m = 16; m; m >>= 1) d2 += __shfl_xor(d2, m);

    // ---- Poincare distance ----
    float dn  = fmaxf((1.0f - hd2) * (1.0f - tl2), EPSF);
    float arg = fmaxf(1.0f + 2.0f * d2 / dn, 1.0f + 1e-7f);
    float dist = acoshf(arg);

    if (lane == 0) {
        out[e] = bias0[hi] + bias1[ti] - dist;
    }
}

extern "C" void kernel_launch(void* const* d_in, const int* in_sizes, int n_in,
                              void* d_out, int out_size, void* d_ws, size_t ws_size,
                              hipStream_t stream) {
    const float* Eh      = (const float*)d_in[0];
    const float* rvh     = (const float*)d_in[1];
    const float* W       = (const float*)d_in[2];
    const float* bias0   = (const float*)d_in[3];
    const float* bias1   = (const float*)d_in[4];
    const int*   head_idx = (const int*)d_in[5];
    const int*   rel_idx  = (const int*)d_in[6];
    const int*   tail_idx = (const int*)d_in[7];
    float* out = (float*)d_out;

    const int total = in_sizes[5];           // B*K = 262144
    const int blocks = (total + 7) / 8;      // 8 elements (32-lane groups) per 256-thr block

    poincare_score_kernel<<<blocks, 256, 0, stream>>>(
        Eh, rvh, W, bias0, bias1, head_idx, rel_idx, tail_idx, out, total);
}

// Round 2
// 48.239 us; speedup vs baseline: 2.1783x; 2.1783x over previous
//
#include <hip/hip_runtime.h>
#include <math.h>

// Poincare-ball KG scoring (MuRP-style) for MI355X, v2.
// 4 lanes per output element; single streaming pass computes 7 raw dot
// products; everything downstream is scalar algebra:
//   hd_d = b * h_d * w_d          (log map -> *w -> exp map -> ball proj)
//   tl_d = p * t_d + q * r_d      (Mobius addition -> ball proj)
//   d2   = hd2 + tl2 - 2 b (p*HWT + q*HWR)

#define EPSF 1e-5f
#define MAXN (1.0f - 1e-5f)

__device__ __forceinline__ float dot4(const float4 a, const float4 b) {
    return a.x * b.x + a.y * b.y + a.z * b.z + a.w * b.w;
}

__global__ __launch_bounds__(256) void poincare_score_kernel(
    const float* __restrict__ Eh, const float* __restrict__ rvh,
    const float* __restrict__ W, const float* __restrict__ bias0,
    const float* __restrict__ bias1, const int* __restrict__ head_idx,
    const int* __restrict__ rel_idx, const int* __restrict__ tail_idx,
    float* __restrict__ out, int total)
{
    const int tid   = threadIdx.x;
    const int lane4 = tid & 3;
    const int e     = blockIdx.x * 64 + (tid >> 2);
    if (e >= total) return;

    const int hi = head_idx[e];
    const int ri = rel_idx[e];
    const int ti = tail_idx[e];

    const float4* __restrict__ Eh4  = reinterpret_cast<const float4*>(Eh);
    const float4* __restrict__ rvh4 = reinterpret_cast<const float4*>(rvh);
    const float4* __restrict__ W4   = reinterpret_cast<const float4*>(W);

    const float4* __restrict__ hrow = Eh4  + (size_t)hi * 32;
    const float4* __restrict__ trow = Eh4  + (size_t)ti * 32;
    const float4* __restrict__ rrow = rvh4 + (size_t)ri * 32;
    const float4* __restrict__ wrow = W4   + (size_t)ri * 32;

    // ---- single pass: 7 raw dot products over D=128 (16 floats per lane) ----
    float H2 = 0.f, T2 = 0.f, R2 = 0.f, TR = 0.f;
    float HW2 = 0.f, HWT = 0.f, HWR = 0.f;
#pragma unroll
    for (int j = 0; j < 8; ++j) {
        const int o = lane4 + j * 4;
        float4 h = hrow[o];
        float4 t = trow[o];
        float4 r = rrow[o];
        float4 w = wrow[o];
        float4 hw;
        hw.x = h.x * w.x; hw.y = h.y * w.y; hw.z = h.z * w.z; hw.w = h.w * w.w;
        H2  += dot4(h, h);
        T2  += dot4(t, t);
        R2  += dot4(r, r);
        TR  += dot4(t, r);
        HW2 += dot4(hw, hw);
        HWT += dot4(hw, t);
        HWR += dot4(hw, r);
    }

    // ---- one batched reduction round across the 4 lanes (2 steps) ----
#pragma unroll
    for (int m = 1; m <= 2; m <<= 1) {
        H2  += __shfl_xor(H2,  m);
        T2  += __shfl_xor(T2,  m);
        R2  += __shfl_xor(R2,  m);
        TR  += __shfl_xor(TR,  m);
        HW2 += __shfl_xor(HW2, m);
        HWT += __shfl_xor(HWT, m);
        HWR += __shfl_xor(HWR, m);
    }

    // ---- scalar finish (replicated over 4 lanes; cheap) ----
    // norm_within_one on h, t, r
    float nh = sqrtf(H2 + 1e-15f);
    float sh = (nh > MAXN) ? (MAXN / nh) : 1.0f;
    float h2 = H2 * sh * sh;

    float nt = sqrtf(T2 + 1e-15f);
    float st = (nt > MAXN) ? (MAXN / nt) : 1.0f;
    float t2 = T2 * st * st;

    float nr = sqrtf(R2 + 1e-15f);
    float sr = (nr > MAXN) ? (MAXN / nr) : 1.0f;
    float r2 = R2 * sr * sr;

    float xy = TR * st * sr;

    // p_log_map(h) then * w:  v_d = a0 * h_d * w_d, a0 = lf * sh
    float nl = sqrtf(h2 + 1e-15f);
    nl = fminf(fmaxf(nl, EPSF), MAXN);
    float lf = 0.5f * logf((1.0f + nl) / (1.0f - nl)) / nl;   // artanh(nl)/nl
    float a0 = lf * sh;
    float v2 = a0 * a0 * HW2;

    // p_exp_map(v):  hd_d = b0 * h_d * w_d, b0 = ef * a0
    float nv = fmaxf(sqrtf(v2 + 1e-15f), EPSF);
    float ef = tanhf(nv) / nv;
    float b0 = ef * a0;
    float hd2 = b0 * b0 * HW2;

    // norm_within_one(head)
    float nhd = sqrtf(hd2 + 1e-15f);
    float shd = (nhd > MAXN) ? (MAXN / nhd) : 1.0f;
    float b = b0 * shd;
    hd2 = b * b * HW2;

    // p_sum(t, r):  tl_d = p * t_d + q * r_d
    float ct  = 1.0f + 2.0f * xy + r2;
    float cr  = 1.0f - t2;
    float den = fmaxf(1.0f + 2.0f * xy + t2 * r2, EPSF);
    float id  = 1.0f / den;
    float p = id * ct * st;
    float q = id * cr * sr;
    float tl2 = p * p * T2 + 2.0f * p * q * TR + q * q * R2;

    // norm_within_one(tail)
    float ntl = sqrtf(tl2 + 1e-15f);
    float stl = (ntl > MAXN) ? (MAXN / ntl) : 1.0f;
    p *= stl; q *= stl;
    tl2 = tl2 * stl * stl;

    // Poincare distance
    float hdtl = b * (p * HWT + q * HWR);      // <head, tail>
    float d2   = hd2 + tl2 - 2.0f * hdtl;
    float dn   = fmaxf((1.0f - hd2) * (1.0f - tl2), EPSF);
    float arg  = fmaxf(1.0f + 2.0f * d2 / dn, 1.0f + 1e-7f);
    float dist = acoshf(arg);

    if (lane4 == 0) {
        out[e] = bias0[hi] + bias1[ti] - dist;
    }
}

extern "C" void kernel_launch(void* const* d_in, const int* in_sizes, int n_in,
                              void* d_out, int out_size, void* d_ws, size_t ws_size,
                              hipStream_t stream) {
    const float* Eh       = (const float*)d_in[0];
    const float* rvh      = (const float*)d_in[1];
    const float* W        = (const float*)d_in[2];
    const float* bias0    = (const float*)d_in[3];
    const float* bias1    = (const float*)d_in[4];
    const int*   head_idx = (const int*)d_in[5];
    const int*   rel_idx  = (const int*)d_in[6];
    const int*   tail_idx = (const int*)d_in[7];
    float* out = (float*)d_out;

    const int total  = in_sizes[5];            // B*K = 262144
    const int blocks = (total + 63) / 64;      // 64 elements (4-lane groups) / 256-thr block

    poincare_score_kernel<<<blocks, 256, 0, stream>>>(
        Eh, rvh, W, bias0, bias1, head_idx, rel_idx, tail_idx, out, total);
}